// Round 1
// baseline (674.096 us; speedup 1.0000x reference)
//
#include <hip/hip_runtime.h>
#include <hip/hip_bf16.h>

// Problem constants (shapes fixed by the reference).
#define DIN  128
#define DHID 128
#define DOUT 64

// ---------------------------------------------------------------------------
// CSR build: count in-degrees, exclusive scan, bucket-fill edge sources.
// ---------------------------------------------------------------------------
__global__ void count_kernel(const int* __restrict__ dst, int* __restrict__ cnt, int E) {
    int e = blockIdx.x * 256 + threadIdx.x;
    if (e < E) atomicAdd(&cnt[dst[e]], 1);
}

__global__ __launch_bounds__(1024)
void scan_kernel(const int* __restrict__ cnt, int* __restrict__ row_ptr, int n) {
    __shared__ int part[1024];
    const int tid = threadIdx.x;
    const int chunk = (n + 1023) / 1024;
    int begin = tid * chunk;
    int end = begin + chunk; if (end > n) end = n;
    int s = 0;
    for (int i = begin; i < end; ++i) s += cnt[i];
    part[tid] = s;
    __syncthreads();
    for (int off = 1; off < 1024; off <<= 1) {
        int v = (tid >= off) ? part[tid - off] : 0;
        __syncthreads();
        part[tid] += v;
        __syncthreads();
    }
    int pre = (tid == 0) ? 0 : part[tid - 1];
    for (int i = begin; i < end; ++i) { row_ptr[i] = pre; pre += cnt[i]; }
    if (tid == 0) row_ptr[n] = part[1023];
}

__global__ void fill_kernel(const int* __restrict__ src, const int* __restrict__ dst,
                            const int* __restrict__ row_ptr, int* __restrict__ fill,
                            int* __restrict__ esrc, int E) {
    int e = blockIdx.x * 256 + threadIdx.x;
    if (e < E) {
        int d = dst[e];
        int pos = row_ptr[d] + atomicAdd(&fill[d], 1);
        esrc[pos] = src[e];
    }
}

// ---------------------------------------------------------------------------
// Mean aggregation: one block per node, 128 threads = one feature channel each.
// Edge-index load is wave-uniform (broadcast); feature gather is coalesced.
// ---------------------------------------------------------------------------
__global__ __launch_bounds__(128)
void agg_kernel(const float* __restrict__ h, const int* __restrict__ row_ptr,
                const int* __restrict__ esrc, float* __restrict__ agg) {
    const int node = blockIdx.x;
    const int c = threadIdx.x;
    const int s = row_ptr[node];
    const int e = row_ptr[node + 1];
    float sum = 0.f;
    for (int i = s; i < e; ++i) {
        int sn = esrc[i];
        sum += h[(size_t)sn * 128 + c];
    }
    float d = (float)(e - s);
    agg[(size_t)node * 128 + c] = sum / fmaxf(d, 1.0f);
}

// ---------------------------------------------------------------------------
// Fused dual-GEMM: out = relu_mask( A1@W1 + A2@W2 + b ).
// K = 128 per matrix (two passes), BM=64 rows, BN=128 or 64 cols,
// 256 threads, thread-tile TM=4 x TN=BN/16.
// ---------------------------------------------------------------------------
template<int BN, bool HAS_MASK>
__global__ __launch_bounds__(256)
void sage_gemm(const float* __restrict__ A1, const float* __restrict__ A2,
               const float* __restrict__ W1, const float* __restrict__ W2,
               const float* __restrict__ bias, const float* __restrict__ mask,
               float* __restrict__ out, int n) {
    constexpr int TM = 4;
    constexpr int TN = BN / 16;   // 8 (BN=128) or 4 (BN=64)
    constexpr int BK = 16;
    __shared__ __align__(16) float As[BK][64 + 4];
    __shared__ __align__(16) float Bs[BK][BN + 4];

    const int tid = threadIdx.x;
    const int row_base = blockIdx.x * 64;
    const int col_grp = tid & 15;
    const int row_grp = tid >> 4;
    const int trow = row_grp * TM;
    const int tcol = col_grp * TN;

    float acc[TM][TN];
#pragma unroll
    for (int i = 0; i < TM; ++i)
#pragma unroll
        for (int j = 0; j < TN; ++j) acc[i][j] = 0.f;

    for (int m = 0; m < 2; ++m) {
        const float* __restrict__ A = (m == 0) ? A1 : A2;
        const float* __restrict__ W = (m == 0) ? W1 : W2;
        for (int k0 = 0; k0 < 128; k0 += BK) {
            __syncthreads();
            // A tile: 64 x 16 floats = 256 float4, one per thread.
            {
                int r = tid >> 2;              // 0..63
                int c4 = (tid & 3) * 4;        // 0,4,8,12
                int gr = row_base + r;
                if (gr >= n) gr = n - 1;       // clamp (stores are guarded)
                float4 v = *(const float4*)&A[(size_t)gr * 128 + k0 + c4];
                As[c4 + 0][r] = v.x; As[c4 + 1][r] = v.y;
                As[c4 + 2][r] = v.z; As[c4 + 3][r] = v.w;
            }
            // B tile: 16 x BN floats, fully coalesced float4 rows.
            {
                constexpr int V = (BK * BN / 4) / 256; // 2 or 1
#pragma unroll
                for (int j = 0; j < V; ++j) {
                    int idx = tid + 256 * j;
                    int kk = idx / (BN / 4);
                    int c4 = (idx % (BN / 4)) * 4;
                    float4 v = *(const float4*)&W[(size_t)(k0 + kk) * BN + c4];
                    *(float4*)&Bs[kk][c4] = v;
                }
            }
            __syncthreads();
#pragma unroll
            for (int kk = 0; kk < BK; ++kk) {
                float a[TM], b[TN];
#pragma unroll
                for (int i = 0; i < TM; ++i) a[i] = As[kk][trow + i];
#pragma unroll
                for (int j = 0; j < TN; ++j) b[j] = Bs[kk][tcol + j];
#pragma unroll
                for (int i = 0; i < TM; ++i)
#pragma unroll
                    for (int j = 0; j < TN; ++j)
                        acc[i][j] = fmaf(a[i], b[j], acc[i][j]);
            }
        }
    }

#pragma unroll
    for (int i = 0; i < TM; ++i) {
        int gr = row_base + trow + i;
        if (gr >= n) continue;
#pragma unroll
        for (int j = 0; j < TN; ++j) {
            float z = acc[i][j] + bias[tcol + j];
            if (HAS_MASK) z = fmaxf(z, 0.f) * mask[(size_t)gr * BN + tcol + j];
            out[(size_t)gr * BN + tcol + j] = z;
        }
    }
}

// ---------------------------------------------------------------------------
extern "C" void kernel_launch(void* const* d_in, const int* in_sizes, int n_in,
                              void* d_out, int out_size, void* d_ws, size_t ws_size,
                              hipStream_t stream) {
    const float* x   = (const float*)d_in[0];
    const int*   src = (const int*)d_in[1];
    const int*   dst = (const int*)d_in[2];
    const float* Ws1 = (const float*)d_in[3];
    const float* Wn1 = (const float*)d_in[4];
    const float* b1  = (const float*)d_in[5];
    const float* Ws2 = (const float*)d_in[6];
    const float* Wn2 = (const float*)d_in[7];
    const float* b2  = (const float*)d_in[8];
    const float* Ws3 = (const float*)d_in[9];
    const float* Wn3 = (const float*)d_in[10];
    const float* b3  = (const float*)d_in[11];
    const float* mask1 = (const float*)d_in[12];
    const float* mask2 = (const float*)d_in[13];
    float* out = (float*)d_out;

    const int N = in_sizes[0] / DIN;
    const int E = in_sizes[1];

    // Workspace layout
    char* ws = (char*)d_ws;
    int* cnt     = (int*)ws;                    // N
    int* fill    = cnt + N;                     // N
    int* row_ptr = fill + N;                    // N+1
    int* esrc    = row_ptr + (N + 1);           // E
    size_t int_bytes = (size_t)(3 * N + 1 + E) * sizeof(int);
    int_bytes = (int_bytes + 255) & ~(size_t)255;
    float* agg = (float*)(ws + int_bytes);      // N*128
    float* h1  = agg + (size_t)N * 128;         // N*128
    float* h2  = h1 + (size_t)N * 128;          // N*128

    // --- CSR build ---
    hipMemsetAsync(cnt, 0, (size_t)2 * N * sizeof(int), stream); // cnt + fill
    count_kernel<<<(E + 255) / 256, 256, 0, stream>>>(dst, cnt, E);
    scan_kernel<<<1, 1024, 0, stream>>>(cnt, row_ptr, N);
    fill_kernel<<<(E + 255) / 256, 256, 0, stream>>>(src, dst, row_ptr, fill, esrc, E);

    const int gemm_blocks = (N + 63) / 64;

    // --- Layer 1 ---
    agg_kernel<<<N, 128, 0, stream>>>(x, row_ptr, esrc, agg);
    sage_gemm<128, true><<<gemm_blocks, 256, 0, stream>>>(x, agg, Ws1, Wn1, b1, mask1, h1, N);
    // --- Layer 2 ---
    agg_kernel<<<N, 128, 0, stream>>>(h1, row_ptr, esrc, agg);
    sage_gemm<128, true><<<gemm_blocks, 256, 0, stream>>>(h1, agg, Ws2, Wn2, b2, mask2, h2, N);
    // --- Layer 3 ---
    agg_kernel<<<N, 128, 0, stream>>>(h2, row_ptr, esrc, agg);
    sage_gemm<64, false><<<gemm_blocks, 256, 0, stream>>>(h2, agg, Ws3, Wn3, b3, nullptr, out, N);
}

// Round 2
// 555.788 us; speedup vs baseline: 1.2129x; 1.2129x over previous
//
#include <hip/hip_runtime.h>
#include <hip/hip_bf16.h>

#define DIN  128
#define DHID 128
#define DOUT 64

typedef short short8 __attribute__((ext_vector_type(8)));
typedef float f32x4  __attribute__((ext_vector_type(4)));

__device__ __forceinline__ ushort f2bf(float f) {
    union { float f; uint u; } c; c.f = f;
    uint u = c.u;
    return (ushort)((u + 0x7fff + ((u >> 16) & 1)) >> 16);   // RNE
}
__device__ __forceinline__ float bf2f(uint h16) {
    union { uint u; float f; } c; c.u = h16 << 16;
    return c.f;
}

// ---------------------------------------------------------------------------
// CSR build
// ---------------------------------------------------------------------------
__global__ void count_kernel(const int* __restrict__ dst, int* __restrict__ cnt, int E) {
    int e = blockIdx.x * 256 + threadIdx.x;
    if (e < E) atomicAdd(&cnt[dst[e]], 1);
}

__global__ __launch_bounds__(1024)
void scan_kernel(const int* __restrict__ cnt, int* __restrict__ row_ptr, int n) {
    __shared__ int part[1024];
    const int tid = threadIdx.x;
    const int chunk = (n + 1023) / 1024;
    int begin = tid * chunk;
    int end = begin + chunk; if (end > n) end = n;
    int s = 0;
    for (int i = begin; i < end; ++i) s += cnt[i];
    part[tid] = s;
    __syncthreads();
    for (int off = 1; off < 1024; off <<= 1) {
        int v = (tid >= off) ? part[tid - off] : 0;
        __syncthreads();
        part[tid] += v;
        __syncthreads();
    }
    int pre = (tid == 0) ? 0 : part[tid - 1];
    for (int i = begin; i < end; ++i) { row_ptr[i] = pre; pre += cnt[i]; }
    if (tid == 0) row_ptr[n] = part[1023];
}

__global__ void fill_kernel(const int* __restrict__ src, const int* __restrict__ dst,
                            const int* __restrict__ row_ptr, int* __restrict__ fill,
                            int* __restrict__ esrc, int E) {
    int e = blockIdx.x * 256 + threadIdx.x;
    if (e < E) {
        int d = dst[e];
        int pos = row_ptr[d] + atomicAdd(&fill[d], 1);
        esrc[pos] = src[e];
    }
}

// ---------------------------------------------------------------------------
// fp32 -> bf16 conversion (x input), 4 elements/thread
// ---------------------------------------------------------------------------
__global__ __launch_bounds__(256)
void cvt_bf16(const float* __restrict__ x, ushort* __restrict__ xb, int n4) {
    int i = blockIdx.x * 256 + threadIdx.x;
    if (i < n4) {
        float4 v = ((const float4*)x)[i];
        ushort4 o;
        o.x = f2bf(v.x); o.y = f2bf(v.y); o.z = f2bf(v.z); o.w = f2bf(v.w);
        ((ushort4*)xb)[i] = o;
    }
}

// ---------------------------------------------------------------------------
// Weight prep: Wt[n][k] = bf16( cat(W_self, W_neigh)[k][n] ), k in [0,256)
// Writes coalesced (consecutive tid -> consecutive k).
// ---------------------------------------------------------------------------
template<int BN>
__global__ __launch_bounds__(256)
void prep_w(const float* __restrict__ Wself, const float* __restrict__ Wneigh,
            ushort* __restrict__ Wt) {
    int idx = blockIdx.x * 256 + threadIdx.x;   // [0, 256*BN)
    int k = idx & 255;
    int n = idx >> 8;
    float v = (k < 128) ? Wself[(size_t)k * BN + n] : Wneigh[(size_t)(k - 128) * BN + n];
    Wt[idx] = f2bf(v);
}

// ---------------------------------------------------------------------------
// Mean aggregation in bf16: one wave per node, lane handles 2 channels (4B).
// One 256B coalesced transaction per neighbor row.
// ---------------------------------------------------------------------------
__global__ __launch_bounds__(256)
void agg_bf16(const ushort* __restrict__ hb, const int* __restrict__ row_ptr,
              const int* __restrict__ esrc, ushort* __restrict__ aggb, int nn) {
    const int wave = threadIdx.x >> 6;
    const int lane = threadIdx.x & 63;
    const int node = blockIdx.x * 4 + wave;
    if (node >= nn) return;
    const int s = row_ptr[node];
    const int e = row_ptr[node + 1];
    float s0 = 0.f, s1 = 0.f;
    for (int i = s; i < e; ++i) {
        int sn = esrc[i];
        uint v = *(const uint*)&hb[(size_t)sn * 128 + lane * 2];
        s0 += bf2f(v & 0xffffu);
        s1 += bf2f(v >> 16);
    }
    float inv = 1.f / fmaxf((float)(e - s), 1.0f);
    uint lo = f2bf(s0 * inv);
    uint hi = f2bf(s1 * inv);
    *(uint*)&aggb[(size_t)node * 128 + lane * 2] = lo | (hi << 16);
}

// ---------------------------------------------------------------------------
// MFMA dual-GEMM: out = post( [Aself|Aneigh] @ Wcat + b ).
// K=256 (two bf16 sources), block tile 128 x BN, 4 waves, each wave 32 rows.
// Per k0-chunk (BK=32) stage A(128x32) and B(BNx32) in LDS (+8 pad; 80B rows
// keep 16B alignment and a uniform bank spread), one MFMA k-step per chunk.
// ---------------------------------------------------------------------------
template<int BN, bool FINAL>
__global__ __launch_bounds__(256)
void sage_mfma(const ushort* __restrict__ Aself, const ushort* __restrict__ Aneigh,
               const ushort* __restrict__ Wt,  // [BN][256] bf16
               const float* __restrict__ bias, const float* __restrict__ mask,
               void* __restrict__ outv, int n) {
    constexpr int PAD = 40;
    constexpr int NT  = BN / 16;            // 8 or 4
    __shared__ ushort As[128][PAD];
    __shared__ ushort Bs[BN][PAD];

    const int tid  = threadIdx.x;
    const int lane = tid & 63;
    const int wave = tid >> 6;
    const int row_base = blockIdx.x * 128;
    const int wrow = wave * 32;
    const int m16  = lane & 15;
    const int kb   = lane >> 4;             // 0..3

    f32x4 acc[2][NT];
#pragma unroll
    for (int i = 0; i < 2; ++i)
#pragma unroll
        for (int j = 0; j < NT; ++j) acc[i][j] = (f32x4)(0.f);

    for (int k0 = 0; k0 < 256; k0 += 32) {
        const ushort* __restrict__ A = (k0 < 128) ? Aself : Aneigh;
        const int ka = k0 & 127;
        __syncthreads();
        // A tile: 128 rows x 32 cols = 512 x 16B segments, 2 per thread
#pragma unroll
        for (int it = 0; it < 2; ++it) {
            int seg = tid + 256 * it;
            int r = seg >> 2;
            int s4 = seg & 3;
            int gr = row_base + r; if (gr >= n) gr = n - 1;
            uint4 v = *(const uint4*)&A[(size_t)gr * 128 + ka + s4 * 8];
            *(uint4*)&As[r][s4 * 8] = v;
        }
        // B tile: BN rows x 32 cols
#pragma unroll
        for (int it = 0; it < (BN * 4) / 256; ++it) {
            int seg = tid + 256 * it;
            int r = seg >> 2;
            int s4 = seg & 3;
            uint4 v = *(const uint4*)&Wt[(size_t)r * 256 + k0 + s4 * 8];
            *(uint4*)&Bs[r][s4 * 8] = v;
        }
        __syncthreads();

        short8 a0 = *(const short8*)&As[wrow + m16][kb * 8];
        short8 a1 = *(const short8*)&As[wrow + 16 + m16][kb * 8];
#pragma unroll
        for (int nt = 0; nt < NT; ++nt) {
            short8 b = *(const short8*)&Bs[nt * 16 + m16][kb * 8];
            acc[0][nt] = __builtin_amdgcn_mfma_f32_16x16x32_bf16(a0, b, acc[0][nt], 0, 0, 0);
            acc[1][nt] = __builtin_amdgcn_mfma_f32_16x16x32_bf16(a1, b, acc[1][nt], 0, 0, 0);
        }
    }

    // Epilogue: C/D layout col = lane&15, row = (lane>>4)*4 + reg
#pragma unroll
    for (int mt = 0; mt < 2; ++mt) {
#pragma unroll
        for (int r = 0; r < 4; ++r) {
            int grow = row_base + wrow + mt * 16 + kb * 4 + r;
            if (grow >= n) continue;
#pragma unroll
            for (int nt = 0; nt < NT; ++nt) {
                int col = nt * 16 + m16;
                float z = acc[mt][nt][r] + bias[col];
                if (!FINAL) {
                    z = fmaxf(z, 0.f) * mask[(size_t)grow * BN + col];
                    ((ushort*)outv)[(size_t)grow * BN + col] = f2bf(z);
                } else {
                    ((float*)outv)[(size_t)grow * BN + col] = z;
                }
            }
        }
    }
}

// ---------------------------------------------------------------------------
extern "C" void kernel_launch(void* const* d_in, const int* in_sizes, int n_in,
                              void* d_out, int out_size, void* d_ws, size_t ws_size,
                              hipStream_t stream) {
    const float* x   = (const float*)d_in[0];
    const int*   src = (const int*)d_in[1];
    const int*   dst = (const int*)d_in[2];
    const float* Ws1 = (const float*)d_in[3];
    const float* Wn1 = (const float*)d_in[4];
    const float* b1  = (const float*)d_in[5];
    const float* Ws2 = (const float*)d_in[6];
    const float* Wn2 = (const float*)d_in[7];
    const float* b2  = (const float*)d_in[8];
    const float* Ws3 = (const float*)d_in[9];
    const float* Wn3 = (const float*)d_in[10];
    const float* b3  = (const float*)d_in[11];
    const float* mask1 = (const float*)d_in[12];
    const float* mask2 = (const float*)d_in[13];
    float* out = (float*)d_out;

    const int N = in_sizes[0] / DIN;
    const int E = in_sizes[1];

    // Workspace layout
    char* ws = (char*)d_ws;
    int* cnt     = (int*)ws;                    // N
    int* fill    = cnt + N;                     // N
    int* row_ptr = fill + N;                    // N+1
    int* esrc    = row_ptr + (N + 1);           // E
    size_t off = ((size_t)(3 * N + 1 + E) * sizeof(int) + 255) & ~(size_t)255;
    ushort* xb   = (ushort*)(ws + off);  off += (size_t)N * 128 * 2;
    ushort* h1b  = (ushort*)(ws + off);  off += (size_t)N * 128 * 2;
    ushort* h2b  = (ushort*)(ws + off);  off += (size_t)N * 128 * 2;
    ushort* aggb = (ushort*)(ws + off);  off += (size_t)N * 128 * 2;
    ushort* Wt1  = (ushort*)(ws + off);  off += 256 * 128 * 2;
    ushort* Wt2  = (ushort*)(ws + off);  off += 256 * 128 * 2;
    ushort* Wt3  = (ushort*)(ws + off);  off += 256 * 64 * 2;

    // --- CSR build ---
    hipMemsetAsync(cnt, 0, (size_t)2 * N * sizeof(int), stream); // cnt + fill
    count_kernel<<<(E + 255) / 256, 256, 0, stream>>>(dst, cnt, E);
    scan_kernel<<<1, 1024, 0, stream>>>(cnt, row_ptr, N);
    fill_kernel<<<(E + 255) / 256, 256, 0, stream>>>(src, dst, row_ptr, fill, esrc, E);

    // --- Prep: x -> bf16, weights -> bf16 transposed-concat ---
    cvt_bf16<<<(N * 128 / 4 + 255) / 256, 256, 0, stream>>>(x, xb, N * 128 / 4);
    prep_w<128><<<128, 256, 0, stream>>>(Ws1, Wn1, Wt1);
    prep_w<128><<<128, 256, 0, stream>>>(Ws2, Wn2, Wt2);
    prep_w<64><<<64, 256, 0, stream>>>(Ws3, Wn3, Wt3);

    const int agg_blocks  = (N + 3) / 4;
    const int gemm_blocks = (N + 127) / 128;

    // --- Layer 1 ---
    agg_bf16<<<agg_blocks, 256, 0, stream>>>(xb, row_ptr, esrc, aggb, N);
    sage_mfma<128, false><<<gemm_blocks, 256, 0, stream>>>(xb, aggb, Wt1, b1, mask1, h1b, N);
    // --- Layer 2 ---
    agg_bf16<<<agg_blocks, 256, 0, stream>>>(h1b, row_ptr, esrc, aggb, N);
    sage_mfma<128, false><<<gemm_blocks, 256, 0, stream>>>(h1b, aggb, Wt2, b2, mask2, h2b, N);
    // --- Layer 3 ---
    agg_bf16<<<agg_blocks, 256, 0, stream>>>(h2b, row_ptr, esrc, aggb, N);
    sage_mfma<64, true><<<gemm_blocks, 256, 0, stream>>>(h2b, aggb, Wt3, b3, nullptr, out, N);
}

// Round 3
// 532.186 us; speedup vs baseline: 1.2667x; 1.0443x over previous
//
#include <hip/hip_runtime.h>
#include <hip/hip_bf16.h>

#define DIN  128
#define DHID 128
#define DOUT 64

typedef short short8 __attribute__((ext_vector_type(8)));
typedef float f32x4  __attribute__((ext_vector_type(4)));

__device__ __forceinline__ ushort f2bf(float f) {
    union { float f; uint u; } c; c.f = f;
    uint u = c.u;
    return (ushort)((u + 0x7fff + ((u >> 16) & 1)) >> 16);   // RNE
}
__device__ __forceinline__ float bf2f(uint h16) {
    union { uint u; float f; } c; c.u = h16 << 16;
    return c.f;
}

// ---------------------------------------------------------------------------
// CSR build
// ---------------------------------------------------------------------------
__global__ void count_kernel(const int* __restrict__ dst, int* __restrict__ cnt, int E) {
    int e = blockIdx.x * 256 + threadIdx.x;
    if (e < E) atomicAdd(&cnt[dst[e]], 1);
}

__global__ __launch_bounds__(1024)
void scan_kernel(const int* __restrict__ cnt, int* __restrict__ row_ptr, int n) {
    __shared__ int part[1024];
    const int tid = threadIdx.x;
    const int chunk = (n + 1023) / 1024;
    int begin = tid * chunk;
    int end = begin + chunk; if (end > n) end = n;
    int s = 0;
    for (int i = begin; i < end; ++i) s += cnt[i];
    part[tid] = s;
    __syncthreads();
    for (int off = 1; off < 1024; off <<= 1) {
        int v = (tid >= off) ? part[tid - off] : 0;
        __syncthreads();
        part[tid] += v;
        __syncthreads();
    }
    int pre = (tid == 0) ? 0 : part[tid - 1];
    for (int i = begin; i < end; ++i) { row_ptr[i] = pre; pre += cnt[i]; }
    if (tid == 0) row_ptr[n] = part[1023];
}

__global__ void fill_kernel(const int* __restrict__ src, const int* __restrict__ dst,
                            const int* __restrict__ row_ptr, int* __restrict__ fill,
                            int* __restrict__ esrc, int E) {
    int e = blockIdx.x * 256 + threadIdx.x;
    if (e < E) {
        int d = dst[e];
        int pos = row_ptr[d] + atomicAdd(&fill[d], 1);
        esrc[pos] = src[e];
    }
}

// ---------------------------------------------------------------------------
// fp32 -> bf16 conversion (x input)
// ---------------------------------------------------------------------------
__global__ __launch_bounds__(256)
void cvt_bf16(const float* __restrict__ x, ushort* __restrict__ xb, int n4) {
    int i = blockIdx.x * 256 + threadIdx.x;
    if (i < n4) {
        float4 v = ((const float4*)x)[i];
        ushort4 o;
        o.x = f2bf(v.x); o.y = f2bf(v.y); o.z = f2bf(v.z); o.w = f2bf(v.w);
        ((ushort4*)xb)[i] = o;
    }
}

// ---------------------------------------------------------------------------
// Weight prep: Wt[n][k] = bf16( cat(W_self, W_neigh)[k][n] ), k in [0,256)
// ---------------------------------------------------------------------------
template<int BN>
__global__ __launch_bounds__(256)
void prep_w(const float* __restrict__ Wself, const float* __restrict__ Wneigh,
            ushort* __restrict__ Wt) {
    int idx = blockIdx.x * 256 + threadIdx.x;   // [0, 256*BN)
    int k = idx & 255;
    int n = idx >> 8;
    float v = (k < 128) ? Wself[(size_t)k * BN + n] : Wneigh[(size_t)(k - 128) * BN + n];
    Wt[idx] = f2bf(v);
}

// ---------------------------------------------------------------------------
// Fused layer: per block of 32 nodes —
//   Phase 1: mean-aggregate neighbors into LDS (bf16). Half-wave per edge
//            (32 lanes x 8B = one 256B row), 2 edges/instr, unrolled x2.
//   Phase 2: dual GEMM [A_self | A_agg] @ Wt (K=256) on mfma_16x16x32_bf16.
//            A_self + W read straight from global (L2-hot), A_agg from LDS.
// ---------------------------------------------------------------------------
template<int BN, bool FINAL>
__global__ __launch_bounds__(256)
void sage_fused(const ushort* __restrict__ hb,      // [n][128] bf16
                const int* __restrict__ row_ptr, const int* __restrict__ esrc,
                const ushort* __restrict__ Wt,      // [BN][256] bf16
                const float* __restrict__ bias, const float* __restrict__ mask,
                void* __restrict__ outv, int n) {
    constexpr int NT2 = BN / 32;       // n-tiles per wave: 4 (BN=128) or 2
    constexpr int STR = 136;           // LDS row stride (ushorts): 272B, 16B-mult, 2-way banks
    __shared__ ushort agg_s[32 * STR];

    const int tid  = threadIdx.x;
    const int lane = tid & 63;
    const int wave = tid >> 6;
    const int base = blockIdx.x * 32;
    const int half = lane >> 5;
    const int l32  = lane & 31;

    // ---- Phase 1: each wave aggregates 8 nodes ----
    for (int j = 0; j < 8; ++j) {
        const int node = base + wave * 8 + j;
        if (node < n) {
            const int s = row_ptr[node];
            const int e = row_ptr[node + 1];
            float4 a0 = make_float4(0.f, 0.f, 0.f, 0.f);
            float4 a1 = make_float4(0.f, 0.f, 0.f, 0.f);
            int i = s + half;
            for (; i + 2 < e; i += 4) {      // 2 gathers in flight per half-wave
                int sn0 = esrc[i];
                int sn1 = esrc[i + 2];
                uint2 v0 = *(const uint2*)&hb[(size_t)sn0 * 128 + l32 * 4];
                uint2 v1 = *(const uint2*)&hb[(size_t)sn1 * 128 + l32 * 4];
                a0.x += bf2f(v0.x & 0xffffu); a0.y += bf2f(v0.x >> 16);
                a0.z += bf2f(v0.y & 0xffffu); a0.w += bf2f(v0.y >> 16);
                a1.x += bf2f(v1.x & 0xffffu); a1.y += bf2f(v1.x >> 16);
                a1.z += bf2f(v1.y & 0xffffu); a1.w += bf2f(v1.y >> 16);
            }
            for (; i < e; i += 2) {
                int sn = esrc[i];
                uint2 v = *(const uint2*)&hb[(size_t)sn * 128 + l32 * 4];
                a0.x += bf2f(v.x & 0xffffu); a0.y += bf2f(v.x >> 16);
                a0.z += bf2f(v.y & 0xffffu); a0.w += bf2f(v.y >> 16);
            }
            a0.x += a1.x; a0.y += a1.y; a0.z += a1.z; a0.w += a1.w;
            a0.x += __shfl_xor(a0.x, 32);
            a0.y += __shfl_xor(a0.y, 32);
            a0.z += __shfl_xor(a0.z, 32);
            a0.w += __shfl_xor(a0.w, 32);
            if (half == 0) {
                float inv = 1.f / fmaxf((float)(e - s), 1.f);
                uint lo = (uint)f2bf(a0.x * inv) | ((uint)f2bf(a0.y * inv) << 16);
                uint hi = (uint)f2bf(a0.z * inv) | ((uint)f2bf(a0.w * inv) << 16);
                uint2 pk; pk.x = lo; pk.y = hi;
                *(uint2*)&agg_s[(wave * 8 + j) * STR + l32 * 4] = pk;
            }
        }
    }
    __syncthreads();

    // ---- Phase 2: dual GEMM ----
    const int m16 = lane & 15;         // A row / B row / D col within tile
    const int kb  = lane >> 4;         // 0..3 k-block; D row quad
    const int mt  = wave & 1;          // m-tile (2 x 16 rows)
    const int nb  = (wave >> 1) * (BN / 2);

    int arow = base + mt * 16 + m16;
    if (arow >= n) arow = n - 1;       // clamp; stores guarded below
    const ushort* __restrict__ aself = &hb[(size_t)arow * 128 + kb * 8];
    const ushort* __restrict__ alds  = &agg_s[(mt * 16 + m16) * STR + kb * 8];

    f32x4 acc[NT2];
#pragma unroll
    for (int t = 0; t < NT2; ++t) acc[t] = (f32x4)(0.f);

#pragma unroll
    for (int c = 0; c < 8; ++c) {      // 8 k-chunks of 32
        short8 a;
        if (c < 4) a = *(const short8*)(aself + c * 32);
        else       a = *(const short8*)(alds + (c - 4) * 32);
#pragma unroll
        for (int t = 0; t < NT2; ++t) {
            short8 b = *(const short8*)&Wt[(size_t)(nb + t * 16 + m16) * 256 + c * 32 + kb * 8];
            acc[t] = __builtin_amdgcn_mfma_f32_16x16x32_bf16(a, b, acc[t], 0, 0, 0);
        }
    }

    // ---- Epilogue: D col = lane&15, row = (lane>>4)*4 + reg ----
#pragma unroll
    for (int t = 0; t < NT2; ++t) {
        const int col = nb + t * 16 + m16;
        const float bcol = bias[col];
#pragma unroll
        for (int r = 0; r < 4; ++r) {
            const int grow = base + mt * 16 + kb * 4 + r;
            if (grow >= n) continue;
            float z = acc[t][r] + bcol;
            if (!FINAL) {
                z = fmaxf(z, 0.f) * mask[(size_t)grow * 128 + col];
                ((ushort*)outv)[(size_t)grow * 128 + col] = f2bf(z);
            } else {
                ((float*)outv)[(size_t)grow * 64 + col] = z;
            }
        }
    }
}

// ---------------------------------------------------------------------------
extern "C" void kernel_launch(void* const* d_in, const int* in_sizes, int n_in,
                              void* d_out, int out_size, void* d_ws, size_t ws_size,
                              hipStream_t stream) {
    const float* x   = (const float*)d_in[0];
    const int*   src = (const int*)d_in[1];
    const int*   dst = (const int*)d_in[2];
    const float* Ws1 = (const float*)d_in[3];
    const float* Wn1 = (const float*)d_in[4];
    const float* b1  = (const float*)d_in[5];
    const float* Ws2 = (const float*)d_in[6];
    const float* Wn2 = (const float*)d_in[7];
    const float* b2  = (const float*)d_in[8];
    const float* Ws3 = (const float*)d_in[9];
    const float* Wn3 = (const float*)d_in[10];
    const float* b3  = (const float*)d_in[11];
    const float* mask1 = (const float*)d_in[12];
    const float* mask2 = (const float*)d_in[13];
    float* out = (float*)d_out;

    const int N = in_sizes[0] / DIN;
    const int E = in_sizes[1];

    // Workspace layout
    char* ws = (char*)d_ws;
    int* cnt     = (int*)ws;                    // N
    int* fill    = cnt + N;                     // N
    int* row_ptr = fill + N;                    // N+1
    int* esrc    = row_ptr + (N + 1);           // E
    size_t off = ((size_t)(3 * N + 1 + E) * sizeof(int) + 255) & ~(size_t)255;
    ushort* xb   = (ushort*)(ws + off);  off += (size_t)N * 128 * 2;
    ushort* h1b  = (ushort*)(ws + off);  off += (size_t)N * 128 * 2;
    ushort* h2b  = (ushort*)(ws + off);  off += (size_t)N * 128 * 2;
    ushort* Wt1  = (ushort*)(ws + off);  off += 256 * 128 * 2;
    ushort* Wt2  = (ushort*)(ws + off);  off += 256 * 128 * 2;
    ushort* Wt3  = (ushort*)(ws + off);  off += 256 * 64 * 2;

    // --- CSR build ---
    hipMemsetAsync(cnt, 0, (size_t)2 * N * sizeof(int), stream); // cnt + fill
    count_kernel<<<(E + 255) / 256, 256, 0, stream>>>(dst, cnt, E);
    scan_kernel<<<1, 1024, 0, stream>>>(cnt, row_ptr, N);
    fill_kernel<<<(E + 255) / 256, 256, 0, stream>>>(src, dst, row_ptr, fill, esrc, E);

    // --- Prep ---
    cvt_bf16<<<(N * 128 / 4 + 255) / 256, 256, 0, stream>>>(x, xb, N * 128 / 4);
    prep_w<128><<<128, 256, 0, stream>>>(Ws1, Wn1, Wt1);
    prep_w<128><<<128, 256, 0, stream>>>(Ws2, Wn2, Wt2);
    prep_w<64><<<64, 256, 0, stream>>>(Ws3, Wn3, Wt3);

    const int blocks = (N + 31) / 32;

    sage_fused<128, false><<<blocks, 256, 0, stream>>>(xb,  row_ptr, esrc, Wt1, b1, mask1, h1b, N);
    sage_fused<128, false><<<blocks, 256, 0, stream>>>(h1b, row_ptr, esrc, Wt2, b2, mask2, h2b, N);
    sage_fused<64,  true ><<<blocks, 256, 0, stream>>>(h2b, row_ptr, esrc, Wt3, b3, nullptr, out, N);
}

// Round 4
// 409.233 us; speedup vs baseline: 1.6472x; 1.3004x over previous
//
#include <hip/hip_runtime.h>
#include <hip/hip_bf16.h>

#define DIN  128
#define DHID 128
#define DOUT 64

typedef short short8 __attribute__((ext_vector_type(8)));
typedef float f32x4  __attribute__((ext_vector_type(4)));

__device__ __forceinline__ ushort f2bf(float f) {
    union { float f; uint u; } c; c.f = f;
    uint u = c.u;
    return (ushort)((u + 0x7fff + ((u >> 16) & 1)) >> 16);   // RNE
}
__device__ __forceinline__ float bf2f(uint h16) {
    union { uint u; float f; } c; c.u = h16 << 16;
    return c.f;
}

// ---------------------------------------------------------------------------
// CSR build: count -> 3-kernel multi-block exclusive scan -> bucket fill
// ---------------------------------------------------------------------------
__global__ void count_kernel(const int* __restrict__ dst, int* __restrict__ cnt, int E) {
    int e = blockIdx.x * 256 + threadIdx.x;
    if (e < E) atomicAdd(&cnt[dst[e]], 1);
}

// Each block sums 512 counts -> bsum[b]
__global__ __launch_bounds__(256)
void scan_part(const int* __restrict__ cnt, int* __restrict__ bsum, int n) {
    __shared__ int red[256];
    int t = threadIdx.x;
    int i = blockIdx.x * 512 + t;
    int v = (i < n) ? cnt[i] : 0;
    if (i + 256 < n) v += cnt[i + 256];
    red[t] = v;
    __syncthreads();
    for (int o = 128; o > 0; o >>= 1) {
        if (t < o) red[t] += red[t + o];
        __syncthreads();
    }
    if (t == 0) bsum[blockIdx.x] = red[0];
}

// Single block (128 threads) exclusive-scans bsum (nb <= 128); writes row_ptr[n]=total
__global__ __launch_bounds__(128)
void scan_top(int* __restrict__ bsum, int nb, int* __restrict__ row_ptr, int n) {
    __shared__ int s[128];
    int t = threadIdx.x;
    int v = (t < nb) ? bsum[t] : 0;
    s[t] = v;
    __syncthreads();
    for (int o = 1; o < 128; o <<= 1) {
        int u = (t >= o) ? s[t - o] : 0;
        __syncthreads();
        s[t] += u;
        __syncthreads();
    }
    if (t < nb) bsum[t] = s[t] - v;      // exclusive
    if (t == 127) row_ptr[n] = s[127];   // total
}

// Each block scans its 512 counts locally, adds block offset, writes row_ptr
__global__ __launch_bounds__(256)
void scan_final(const int* __restrict__ cnt, const int* __restrict__ bsum,
                int* __restrict__ row_ptr, int n) {
    __shared__ int s[256];
    int t = threadIdx.x;
    int i0 = blockIdx.x * 512 + t * 2;
    int c0 = (i0 < n) ? cnt[i0] : 0;
    int c1 = (i0 + 1 < n) ? cnt[i0 + 1] : 0;
    s[t] = c0 + c1;
    __syncthreads();
    for (int o = 1; o < 256; o <<= 1) {           // inclusive Hillis-Steele
        int u = (t >= o) ? s[t - o] : 0;
        __syncthreads();
        s[t] += u;
        __syncthreads();
    }
    int pre = bsum[blockIdx.x] + ((t > 0) ? s[t - 1] : 0);
    if (i0 < n) row_ptr[i0] = pre;
    if (i0 + 1 < n) row_ptr[i0 + 1] = pre + c0;
}

__global__ void fill_kernel(const int* __restrict__ src, const int* __restrict__ dst,
                            const int* __restrict__ row_ptr, int* __restrict__ fill,
                            int* __restrict__ esrc, int E) {
    int e = blockIdx.x * 256 + threadIdx.x;
    if (e < E) {
        int d = dst[e];
        int pos = row_ptr[d] + atomicAdd(&fill[d], 1);
        esrc[pos] = src[e];
    }
}

// ---------------------------------------------------------------------------
// fp32 -> bf16 conversion (x input)
// ---------------------------------------------------------------------------
__global__ __launch_bounds__(256)
void cvt_bf16(const float* __restrict__ x, ushort* __restrict__ xb, int n4) {
    int i = blockIdx.x * 256 + threadIdx.x;
    if (i < n4) {
        float4 v = ((const float4*)x)[i];
        ushort4 o;
        o.x = f2bf(v.x); o.y = f2bf(v.y); o.z = f2bf(v.z); o.w = f2bf(v.w);
        ((ushort4*)xb)[i] = o;
    }
}

// ---------------------------------------------------------------------------
// Weight prep: Wt[n][k] = bf16( cat(W_self, W_neigh)[k][n] ), k in [0,256)
// ---------------------------------------------------------------------------
template<int BN>
__global__ __launch_bounds__(256)
void prep_w(const float* __restrict__ Wself, const float* __restrict__ Wneigh,
            ushort* __restrict__ Wt) {
    int idx = blockIdx.x * 256 + threadIdx.x;   // [0, 256*BN)
    int k = idx & 255;
    int n = idx >> 8;
    float v = (k < 128) ? Wself[(size_t)k * BN + n] : Wneigh[(size_t)(k - 128) * BN + n];
    Wt[idx] = f2bf(v);
}

// ---------------------------------------------------------------------------
// Fused layer, block = 32 nodes:
//   Phase 1: quarter-wave (16 lanes x 16B = 256B row) per node, 2 nodes per
//            quarter-wave serially, edge loop unrolled x4 -> 16 outstanding
//            256B gathers per wave. Each lane owns 8 channels (no reduce).
//   Phase 2: dual GEMM [A_self | A_agg] @ Wt (K=256) on mfma_16x16x32_bf16.
// ---------------------------------------------------------------------------
template<int BN, bool FINAL>
__global__ __launch_bounds__(256)
void sage_fused(const ushort* __restrict__ hb,      // [n][128] bf16
                const int* __restrict__ row_ptr, const int* __restrict__ esrc,
                const ushort* __restrict__ Wt,      // [BN][256] bf16
                const float* __restrict__ bias, const float* __restrict__ mask,
                void* __restrict__ outv, int n) {
    constexpr int NT2 = BN / 32;       // n-tiles per wave: 4 (BN=128) or 2
    constexpr int STR = 136;           // LDS row stride in ushorts (272B)
    __shared__ ushort agg_s[32 * STR];

    const int tid  = threadIdx.x;
    const int lane = tid & 63;
    const int wave = tid >> 6;
    const int base = blockIdx.x * 32;
    const int qw   = lane >> 4;        // quarter-wave id 0..3
    const int l16  = lane & 15;

    // ---- Phase 1: quarter-wave per node, 2 nodes each ----
#pragma unroll
    for (int j = 0; j < 2; ++j) {
        const int local = wave * 8 + qw * 2 + j;
        const int node = base + local;
        if (node < n) {
            const int s = row_ptr[node];
            const int e = row_ptr[node + 1];
            const ushort* __restrict__ hbl = hb + l16 * 8;
            float4 a0 = make_float4(0.f, 0.f, 0.f, 0.f);
            float4 a1 = make_float4(0.f, 0.f, 0.f, 0.f);
            int i = s;
            for (; i + 3 < e; i += 4) {    // 4 gathers in flight
                int sn0 = esrc[i];
                int sn1 = esrc[i + 1];
                int sn2 = esrc[i + 2];
                int sn3 = esrc[i + 3];
                uint4 v0 = *(const uint4*)&hbl[(size_t)sn0 * 128];
                uint4 v1 = *(const uint4*)&hbl[(size_t)sn1 * 128];
                uint4 v2 = *(const uint4*)&hbl[(size_t)sn2 * 128];
                uint4 v3 = *(const uint4*)&hbl[(size_t)sn3 * 128];
                a0.x += bf2f(v0.x & 0xffffu) + bf2f(v1.x & 0xffffu);
                a0.y += bf2f(v0.x >> 16)     + bf2f(v1.x >> 16);
                a0.z += bf2f(v0.y & 0xffffu) + bf2f(v1.y & 0xffffu);
                a0.w += bf2f(v0.y >> 16)     + bf2f(v1.y >> 16);
                a1.x += bf2f(v0.z & 0xffffu) + bf2f(v1.z & 0xffffu);
                a1.y += bf2f(v0.z >> 16)     + bf2f(v1.z >> 16);
                a1.z += bf2f(v0.w & 0xffffu) + bf2f(v1.w & 0xffffu);
                a1.w += bf2f(v0.w >> 16)     + bf2f(v1.w >> 16);
                a0.x += bf2f(v2.x & 0xffffu) + bf2f(v3.x & 0xffffu);
                a0.y += bf2f(v2.x >> 16)     + bf2f(v3.x >> 16);
                a0.z += bf2f(v2.y & 0xffffu) + bf2f(v3.y & 0xffffu);
                a0.w += bf2f(v2.y >> 16)     + bf2f(v3.y >> 16);
                a1.x += bf2f(v2.z & 0xffffu) + bf2f(v3.z & 0xffffu);
                a1.y += bf2f(v2.z >> 16)     + bf2f(v3.z >> 16);
                a1.z += bf2f(v2.w & 0xffffu) + bf2f(v3.w & 0xffffu);
                a1.w += bf2f(v2.w >> 16)     + bf2f(v3.w >> 16);
            }
            for (; i < e; ++i) {
                int sn = esrc[i];
                uint4 v = *(const uint4*)&hbl[(size_t)sn * 128];
                a0.x += bf2f(v.x & 0xffffu); a0.y += bf2f(v.x >> 16);
                a0.z += bf2f(v.y & 0xffffu); a0.w += bf2f(v.y >> 16);
                a1.x += bf2f(v.z & 0xffffu); a1.y += bf2f(v.z >> 16);
                a1.z += bf2f(v.w & 0xffffu); a1.w += bf2f(v.w >> 16);
            }
            float inv = 1.f / fmaxf((float)(e - s), 1.f);
            uint4 pk;
            pk.x = (uint)f2bf(a0.x * inv) | ((uint)f2bf(a0.y * inv) << 16);
            pk.y = (uint)f2bf(a0.z * inv) | ((uint)f2bf(a0.w * inv) << 16);
            pk.z = (uint)f2bf(a1.x * inv) | ((uint)f2bf(a1.y * inv) << 16);
            pk.w = (uint)f2bf(a1.z * inv) | ((uint)f2bf(a1.w * inv) << 16);
            *(uint4*)&agg_s[local * STR + l16 * 8] = pk;
        }
    }
    __syncthreads();

    // ---- Phase 2: dual GEMM ----
    const int m16 = lane & 15;         // A row / B row / D col within tile
    const int kb  = lane >> 4;         // 0..3 k-block; D row quad
    const int mt  = wave & 1;          // m-tile (2 x 16 rows)
    const int nb  = (wave >> 1) * (BN / 2);

    int arow = base + mt * 16 + m16;
    if (arow >= n) arow = n - 1;       // clamp; stores guarded below
    const ushort* __restrict__ aself = &hb[(size_t)arow * 128 + kb * 8];
    const ushort* __restrict__ alds  = &agg_s[(mt * 16 + m16) * STR + kb * 8];

    f32x4 acc[NT2];
#pragma unroll
    for (int t = 0; t < NT2; ++t) acc[t] = (f32x4)(0.f);

#pragma unroll
    for (int c = 0; c < 8; ++c) {      // 8 k-chunks of 32
        short8 a;
        if (c < 4) a = *(const short8*)(aself + c * 32);
        else       a = *(const short8*)(alds + (c - 4) * 32);
#pragma unroll
        for (int t = 0; t < NT2; ++t) {
            short8 b = *(const short8*)&Wt[(size_t)(nb + t * 16 + m16) * 256 + c * 32 + kb * 8];
            acc[t] = __builtin_amdgcn_mfma_f32_16x16x32_bf16(a, b, acc[t], 0, 0, 0);
        }
    }

    // ---- Epilogue: D col = lane&15, row = (lane>>4)*4 + reg ----
#pragma unroll
    for (int t = 0; t < NT2; ++t) {
        const int col = nb + t * 16 + m16;
        const float bcol = bias[col];
#pragma unroll
        for (int r = 0; r < 4; ++r) {
            const int grow = base + mt * 16 + kb * 4 + r;
            if (grow >= n) continue;
            float z = acc[t][r] + bcol;
            if (!FINAL) {
                z = fmaxf(z, 0.f) * mask[(size_t)grow * 128 + col];
                ((ushort*)outv)[(size_t)grow * 128 + col] = f2bf(z);
            } else {
                ((float*)outv)[(size_t)grow * 64 + col] = z;
            }
        }
    }
}

// ---------------------------------------------------------------------------
extern "C" void kernel_launch(void* const* d_in, const int* in_sizes, int n_in,
                              void* d_out, int out_size, void* d_ws, size_t ws_size,
                              hipStream_t stream) {
    const float* x   = (const float*)d_in[0];
    const int*   src = (const int*)d_in[1];
    const int*   dst = (const int*)d_in[2];
    const float* Ws1 = (const float*)d_in[3];
    const float* Wn1 = (const float*)d_in[4];
    const float* b1  = (const float*)d_in[5];
    const float* Ws2 = (const float*)d_in[6];
    const float* Wn2 = (const float*)d_in[7];
    const float* b2  = (const float*)d_in[8];
    const float* Ws3 = (const float*)d_in[9];
    const float* Wn3 = (const float*)d_in[10];
    const float* b3  = (const float*)d_in[11];
    const float* mask1 = (const float*)d_in[12];
    const float* mask2 = (const float*)d_in[13];
    float* out = (float*)d_out;

    const int N = in_sizes[0] / DIN;
    const int E = in_sizes[1];

    // Workspace layout
    char* ws = (char*)d_ws;
    int* cnt     = (int*)ws;                    // N
    int* fill    = cnt + N;                     // N
    int* row_ptr = fill + N;                    // N+1
    int* esrc    = row_ptr + (N + 1);           // E
    int* bsum    = esrc + E;                    // 128
    size_t off = ((size_t)(3 * N + 1 + E + 128) * sizeof(int) + 255) & ~(size_t)255;
    ushort* xb   = (ushort*)(ws + off);  off += (size_t)N * 128 * 2;
    ushort* h1b  = (ushort*)(ws + off);  off += (size_t)N * 128 * 2;
    ushort* h2b  = (ushort*)(ws + off);  off += (size_t)N * 128 * 2;
    ushort* Wt1  = (ushort*)(ws + off);  off += 256 * 128 * 2;
    ushort* Wt2  = (ushort*)(ws + off);  off += 256 * 128 * 2;
    ushort* Wt3  = (ushort*)(ws + off);  off += 256 * 64 * 2;

    const int nb = (N + 511) / 512;             // 98 for N=50000 (<=128)

    // --- CSR build ---
    hipMemsetAsync(cnt, 0, (size_t)2 * N * sizeof(int), stream); // cnt + fill
    count_kernel<<<(E + 255) / 256, 256, 0, stream>>>(dst, cnt, E);
    scan_part<<<nb, 256, 0, stream>>>(cnt, bsum, N);
    scan_top<<<1, 128, 0, stream>>>(bsum, nb, row_ptr, N);
    scan_final<<<nb, 256, 0, stream>>>(cnt, bsum, row_ptr, N);
    fill_kernel<<<(E + 255) / 256, 256, 0, stream>>>(src, dst, row_ptr, fill, esrc, E);

    // --- Prep ---
    cvt_bf16<<<(N * 128 / 4 + 255) / 256, 256, 0, stream>>>(x, xb, N * 128 / 4);
    prep_w<128><<<128, 256, 0, stream>>>(Ws1, Wn1, Wt1);
    prep_w<128><<<128, 256, 0, stream>>>(Ws2, Wn2, Wt2);
    prep_w<64><<<64, 256, 0, stream>>>(Ws3, Wn3, Wt3);

    const int blocks = (N + 31) / 32;

    sage_fused<128, false><<<blocks, 256, 0, stream>>>(xb,  row_ptr, esrc, Wt1, b1, mask1, h1b, N);
    sage_fused<128, false><<<blocks, 256, 0, stream>>>(h1b, row_ptr, esrc, Wt2, b2, mask2, h2b, N);
    sage_fused<64,  true ><<<blocks, 256, 0, stream>>>(h2b, row_ptr, esrc, Wt3, b3, nullptr, out, N);
}